// Round 1
// 317.214 us; speedup vs baseline: 1.0614x; 1.0614x over previous
//
#include <hip/hip_runtime.h>
#include <math.h>

#define NB 8
#define NN 4096
#define NDIM 512
#define NH 8
#define NDH 64
#define QKVC 1536
#define NROWS (NB * NN)
#define EPSF 1e-5f
#define INV_N (1.0f / 4096.0f)
// log2(10000)/16
#define L2_10K_16 0.8304820237218406f

typedef __bf16 bf16x8_t __attribute__((ext_vector_type(8)));
typedef float f32x4_t __attribute__((ext_vector_type(4)));
typedef unsigned short u16x8 __attribute__((ext_vector_type(8)));

__device__ inline unsigned short f2bf(float f) {
    unsigned u = __builtin_bit_cast(unsigned, f);
    u += 0x7fff + ((u >> 16) & 1);          // round-to-nearest-even
    return (unsigned short)(u >> 16);
}
__device__ inline float bf2f(unsigned short u) {
    unsigned v = (unsigned)u << 16;
    return __builtin_bit_cast(float, v);
}

// async global->LDS, 16B per lane; LDS dest = wave-uniform base + lane*16
#define GLOAD_LDS16(g, s) __builtin_amdgcn_global_load_lds(                    \
    (const __attribute__((address_space(1))) void*)(g),                        \
    (__attribute__((address_space(3))) void*)(s), 16, 0, 0)

// ---------------------------------------------------------------------------
// fp32 -> bf16 convert, 8 elems/thread. n must be multiple of 8.
// ---------------------------------------------------------------------------
__global__ __launch_bounds__(256)
void cvt_bf16_kernel(const float* __restrict__ s, unsigned short* __restrict__ d, int n)
{
    const int i = (blockIdx.x * 256 + threadIdx.x) * 8;
    if (i >= n) return;
    float4 a = *(const float4*)(s + i);
    float4 b = *(const float4*)(s + i + 4);
    ushort4 lo, hi;
    lo.x = f2bf(a.x); lo.y = f2bf(a.y); lo.z = f2bf(a.z); lo.w = f2bf(a.w);
    hi.x = f2bf(b.x); hi.y = f2bf(b.y); hi.z = f2bf(b.z); hi.w = f2bf(b.w);
    *(ushort4*)(d + i)     = lo;
    *(ushort4*)(d + i + 4) = hi;
}

// fp32 -> bf16 with scale (for dots -> dots_bf * 1/N), 4 elems/thread
__global__ __launch_bounds__(256)
void cvt_dots_kernel(const float* __restrict__ s, unsigned short* __restrict__ d)
{
    const int i = (blockIdx.x * 256 + threadIdx.x) * 4;
    float4 a = *(const float4*)(s + i);
    ushort4 o;
    o.x = f2bf(a.x * INV_N); o.y = f2bf(a.y * INV_N);
    o.z = f2bf(a.z * INV_N); o.w = f2bf(a.w * INV_N);
    *(ushort4*)(d + i) = o;
}

// ---------------------------------------------------------------------------
// Fused QKV GEMM, 256x128 tile, BK=64, 8 waves (4M x 2N), 3-deep circular
// LDS pipeline with counted vmcnt (T3+T4), XOR-swizzled LDS (T2, both-sides
// via pre-swizzled global source per rule 21), setprio around MFMA (T5),
// bijective XCD blockIdx swizzle (T1). Epilogue: RoPE(q,k) + LN(k,v), bf16 out.
// Race-freedom: group t reads buf[t%3], stages tile t+2 into buf[(t+2)%3] ==
// buf[(t-1)%3]; tile t-1's ds_reads retired before group t-1's end barrier.
// vmcnt(6) at group end = exactly tile t+1 landed (6 loads/tile in flight).
// ---------------------------------------------------------------------------
__global__ __launch_bounds__(512, 2)
void gemm_qkv_fused(const unsigned short* __restrict__ A,
                    const unsigned short* __restrict__ Bm,
                    const float* __restrict__ pos,
                    const float* __restrict__ gk, const float* __restrict__ bk,
                    const float* __restrict__ gv, const float* __restrict__ bvv,
                    unsigned short* __restrict__ qkvb)
{
    // per buffer: A[256][64] bf16 (32KB) then B[128][64] bf16 (16KB). 3 bufs = 144KB.
    __shared__ __align__(16) unsigned short lds[3 * 24576];

    const int t    = threadIdx.x;
    const int wave = t >> 6;
    const int lane = t & 63;

    // T1: bijective XCD swizzle (nwg = 1536, 1536 % 8 == 0)
    int flat = blockIdx.y * 12 + blockIdx.x;
    flat = (flat & 7) * 192 + (flat >> 3);
    const int bx = flat % 12;
    const int by = flat / 12;
    const int m0 = by * 256;
    const int n0 = bx * 128;

    const int wm = (wave >> 1) * 64;    // 4 M-waves: 0,64,128,192
    const int wn = (wave & 1) * 64;     // 2 N-waves: 0,64
    const int fr = lane & 15;
    const int fq = lane >> 4;           // 0..3
    const int rc = fr & 7;              // row&7 for swizzled frag reads

    // staging: each wave stages 8 rows x 128B per GLOAD call, source chunk
    // pre-swizzled so linear LDS dest == swizzled logical layout (rule 21)
    const int row8 = lane >> 3;               // 0..7 (row within wave's 8)
    const int csrc = (lane & 7) ^ row8;       // swizzled 16B chunk in source
    const unsigned short* Asrc = A  + (size_t)(m0 + wave * 8 + row8) * NDIM + csrc * 8;
    const unsigned short* Bsrc = Bm + (size_t)(n0 + wave * 8 + row8) * NDIM + csrc * 8;

    // tile tt, call a (A: a=0..3 -> rows a*64.., B: b=0..1)
#define STAGE_A(tt, a) GLOAD_LDS16(Asrc + (size_t)(a) * 64 * NDIM + (tt) * 64,   \
        &lds[((tt) % 3) * 24576 + (a) * 4096 + wave * 512])
#define STAGE_B(tt, bb) GLOAD_LDS16(Bsrc + (size_t)(bb) * 64 * NDIM + (tt) * 64, \
        &lds[((tt) % 3) * 24576 + 16384 + (bb) * 4096 + wave * 512])

    f32x4_t acc[4][4] = {};

    // prologue: stage tiles 0,1 (12 loads); wait until tile 0 landed (6 left)
    STAGE_A(0, 0); STAGE_A(0, 1); STAGE_A(0, 2); STAGE_A(0, 3);
    STAGE_B(0, 0); STAGE_B(0, 1);
    STAGE_A(1, 0); STAGE_A(1, 1); STAGE_A(1, 2); STAGE_A(1, 3);
    STAGE_B(1, 0); STAGE_B(1, 1);
    asm volatile("s_waitcnt vmcnt(6)" ::: "memory");
    __builtin_amdgcn_s_barrier();

    #pragma unroll
    for (int tt = 0; tt < 8; ++tt) {
        const unsigned short* Ab = &lds[(tt % 3) * 24576];
        const unsigned short* Bb = Ab + 16384;
        #pragma unroll
        for (int kh = 0; kh < 2; ++kh) {
            const int ch = ((kh << 2) | fq) ^ rc;       // swizzled 16B chunk
            bf16x8_t af[4], bfrag[4];
            #pragma unroll
            for (int mi = 0; mi < 4; ++mi)
                af[mi] = *(const bf16x8_t*)&Ab[(wm + mi * 16 + fr) * 64 + ch * 8];
            #pragma unroll
            for (int nj = 0; nj < 4; ++nj)
                bfrag[nj] = *(const bf16x8_t*)&Bb[(wn + nj * 16 + fr) * 64 + ch * 8];
            if (tt < 6) {                               // stage tile tt+2
                if (kh == 0) { STAGE_A(tt + 2, 0); STAGE_A(tt + 2, 1); STAGE_A(tt + 2, 2); }
                else         { STAGE_A(tt + 2, 3); STAGE_B(tt + 2, 0); STAGE_B(tt + 2, 1); }
            }
            __builtin_amdgcn_s_barrier();
            __builtin_amdgcn_s_setprio(1);
            #pragma unroll
            for (int mi = 0; mi < 4; ++mi)
                #pragma unroll
                for (int nj = 0; nj < 4; ++nj)
                    acc[mi][nj] = __builtin_amdgcn_mfma_f32_16x16x32_bf16(
                        af[mi], bfrag[nj], acc[mi][nj], 0, 0, 0);
            __builtin_amdgcn_s_setprio(0);
            if (kh == 1) {                              // group boundary
                if (tt < 6)       asm volatile("s_waitcnt vmcnt(6)" ::: "memory");
                else if (tt == 6) asm volatile("s_waitcnt vmcnt(0)" ::: "memory");
            }
            __builtin_amdgcn_s_barrier();
        }
    }
#undef STAGE_A
#undef STAGE_B

    // ---- fused epilogue (wave owns 64 rows x 64 cols = one head's d-span) ----
    const int type = (n0 + wn) >> 9;    // 0=q, 1=k, 2=v (uniform per wave)
    const int c  = lane & 15;
    const int g4 = (lane >> 4) * 4;

    if (type != 0) {                    // LN over head dim (k or v)
        const float* gamma = (type == 1) ? gk : gv;
        const float* beta  = (type == 1) ? bk : bvv;
        float gm[4], bt[4];
        #pragma unroll
        for (int j = 0; j < 4; ++j) { gm[j] = gamma[j * 16 + c]; bt[j] = beta[j * 16 + c]; }
        #pragma unroll
        for (int i = 0; i < 4; ++i)
            #pragma unroll
            for (int r = 0; r < 4; ++r) {
                float t0 = acc[i][0][r], t1 = acc[i][1][r];
                float t2 = acc[i][2][r], t3 = acc[i][3][r];
                float s  = t0 + t1 + t2 + t3;
                float ss = t0*t0 + t1*t1 + t2*t2 + t3*t3;
                #pragma unroll
                for (int msk = 1; msk < 16; msk <<= 1) {
                    s  += __shfl_xor(s,  msk, 64);
                    ss += __shfl_xor(ss, msk, 64);
                }
                const float mu = s * (1.0f / 64.0f);
                const float rs = rsqrtf(ss * (1.0f / 64.0f) - mu * mu + EPSF);
                acc[i][0][r] = (t0 - mu) * rs * gm[0] + bt[0];
                acc[i][1][r] = (t1 - mu) * rs * gm[1] + bt[1];
                acc[i][2][r] = (t2 - mu) * rs * gm[2] + bt[2];
                acc[i][3][r] = (t3 - mu) * rs * gm[3] + bt[3];
            }
    }
    if (type != 2) {                    // RoPE 2D (q or k)
        const float Kc = 64.0f * exp2f(-(float)c * L2_10K_16);
        #pragma unroll
        for (int i = 0; i < 4; ++i)
            #pragma unroll
            for (int r = 0; r < 4; ++r) {
                const int row = m0 + wm + i * 16 + g4 + r;
                const float2 p = ((const float2*)pos)[row];
                float sx, cx, sy, cy;
                __sincosf(p.x * Kc, &sx, &cx);
                __sincosf(p.y * Kc, &sy, &cy);
                const float t0 = acc[i][0][r], t1 = acc[i][1][r];
                const float t2 = acc[i][2][r], t3 = acc[i][3][r];
                acc[i][0][r] = t0 * cx - t1 * sx;
                acc[i][1][r] = t1 * cx + t0 * sx;
                acc[i][2][r] = t2 * cy - t3 * sy;
                acc[i][3][r] = t3 * cy + t2 * sy;
            }
    }
    #pragma unroll
    for (int i = 0; i < 4; ++i)
        #pragma unroll
        for (int j = 0; j < 4; ++j) {
            unsigned short* qp = qkvb + (size_t)(m0 + wm + i * 16 + g4) * QKVC
                               + n0 + wn + j * 16 + c;
            #pragma unroll
            for (int r = 0; r < 4; ++r)
                qp[(size_t)r * QKVC] = f2bf(acc[i][j][r]);
        }
}

// ---------------------------------------------------------------------------
// dots[b][h][d][e] = sum_n k[b,h,n,d] * v[b,h,n,e]  (bf16 in, fp32 atomics)
// ---------------------------------------------------------------------------
__global__ __launch_bounds__(256)
void dots_kernel(const unsigned short* __restrict__ qkvb, float* __restrict__ dots)
{
    __shared__ float ks[32][64];
    __shared__ float vs[32][64];
    const int b = blockIdx.z, h = blockIdx.y;
    const int n0 = blockIdx.x * 512;
    const int t = threadIdx.x;
    const int row = t >> 3;            // 0..31
    const int c8  = (t & 7) * 8;
    const int d0 = (t >> 4) * 4;
    const int e0 = (t & 15) * 4;

    float acc[4][4] = {{0.0f}};
    const size_t kbase = (size_t)(b * NN + n0 + row) * QKVC + 512 + h * NDH + c8;
    const size_t vbase = kbase + 512;

    u16x8 ku = *(const u16x8*)(qkvb + kbase);
    u16x8 vu = *(const u16x8*)(qkvb + vbase);

    for (int s = 0; s < 16; ++s) {
        __syncthreads();
        #pragma unroll
        for (int j = 0; j < 8; ++j) {
            ks[row][c8 + j] = bf2f(ku[j]);
            vs[row][c8 + j] = bf2f(vu[j]);
        }
        __syncthreads();
        if (s + 1 < 16) {
            ku = *(const u16x8*)(qkvb + kbase + (size_t)(s + 1) * 32 * QKVC);
            vu = *(const u16x8*)(qkvb + vbase + (size_t)(s + 1) * 32 * QKVC);
        }
        #pragma unroll
        for (int r = 0; r < 32; ++r) {
            float4 kd = *(float4*)&ks[r][d0];
            float4 ve = *(float4*)&vs[r][e0];
            acc[0][0] += kd.x*ve.x; acc[0][1] += kd.x*ve.y; acc[0][2] += kd.x*ve.z; acc[0][3] += kd.x*ve.w;
            acc[1][0] += kd.y*ve.x; acc[1][1] += kd.y*ve.y; acc[1][2] += kd.y*ve.z; acc[1][3] += kd.y*ve.w;
            acc[2][0] += kd.z*ve.x; acc[2][1] += kd.z*ve.y; acc[2][2] += kd.z*ve.z; acc[2][3] += kd.z*ve.w;
            acc[3][0] += kd.w*ve.x; acc[3][1] += kd.w*ve.y; acc[3][2] += kd.w*ve.z; acc[3][3] += kd.w*ve.w;
        }
    }
    float* dp = dots + ((size_t)(b * NH + h) * 64 + d0) * 64 + e0;
    #pragma unroll
    for (int i = 0; i < 4; ++i)
        #pragma unroll
        for (int j = 0; j < 4; ++j)
            atomicAdd(dp + i * 64 + j, acc[i][j]);
}

// ---------------------------------------------------------------------------
// M2b[b][d'][h*64+d] = bf16( sum_e dots_bf[b,h,d,e] * Woutb[d', h*64+e] )
// ---------------------------------------------------------------------------
__global__ __launch_bounds__(256)
void dotsw_mfma(const unsigned short* __restrict__ Woutb,
                const unsigned short* __restrict__ dots_bf,
                unsigned short* __restrict__ M2b)
{
    __shared__ unsigned short As[128 * 64];   // Wout tile, row-major (16 KB)
    __shared__ unsigned short Bs[64 * 64];    // dots[b,h], row-major (8 KB)
    const int t = threadIdx.x;
    const int wave = t >> 6;
    const int lane = t & 63;
    const int dp0 = blockIdx.x * 128;
    const int h = blockIdx.y, b = blockIdx.z;

    const int srow = lane >> 3;               // 0..7
    const int scol = (lane & 7) * 8;
    const unsigned short* Ag = Woutb + (size_t)(dp0 + wave * 32 + srow) * NDIM
                             + h * NDH + scol;
    const unsigned short* Bg = dots_bf + ((size_t)(b * NH + h) * 64 + wave * 16 + srow) * 64
                             + scol;
    #pragma unroll
    for (int i = 0; i < 4; ++i)
        GLOAD_LDS16(Ag + (size_t)i * 8 * NDIM, As + wave * 2048 + i * 512);
    #pragma unroll
    for (int i = 0; i < 2; ++i)
        GLOAD_LDS16(Bg + (size_t)i * 8 * 64, Bs + wave * 1024 + i * 512);
    __syncthreads();

    const int wm = (wave >> 1) * 64;          // d' quadrant
    const int wn = (wave & 1) * 32;           // d half
    const int fr = lane & 15;
    const int fq = (lane >> 4) * 8;

    f32x4_t acc[4][2] = {};
    #pragma unroll
    for (int kk = 0; kk < 2; ++kk) {
        bf16x8_t af[4], bf[2];
        #pragma unroll
        for (int i = 0; i < 4; ++i)
            af[i] = *(const bf16x8_t*)&As[(wm + i * 16 + fr) * 64 + kk * 32 + fq];
        #pragma unroll
        for (int j = 0; j < 2; ++j)
            bf[j] = *(const bf16x8_t*)&Bs[(wn + j * 16 + fr) * 64 + kk * 32 + fq];
        #pragma unroll
        for (int i = 0; i < 4; ++i)
            #pragma unroll
            for (int j = 0; j < 2; ++j)
                acc[i][j] = __builtin_amdgcn_mfma_f32_16x16x32_bf16(
                    af[i], bf[j], acc[i][j], 0, 0, 0);
    }

    const int c  = lane & 15;
    const int g4 = (lane >> 4) * 4;
    #pragma unroll
    for (int i = 0; i < 4; ++i)
        #pragma unroll
        for (int j = 0; j < 2; ++j) {
            unsigned short* mp = M2b + ((size_t)(b * NDIM) + dp0 + wm + i * 16 + g4) * NDIM
                               + h * NDH + wn + j * 16 + c;
            #pragma unroll
            for (int r = 0; r < 4; ++r)
                mp[(size_t)r * NDIM] = f2bf(acc[i][j][r]);
        }
}

// ---------------------------------------------------------------------------
// out[b*NN+m][d'] = sum_hd q[b,m,hd] * M2b[b][d'][hd] + bout[d']   (fp32 out)
// ---------------------------------------------------------------------------
__global__ __launch_bounds__(256)
void gemm_out_mfma(const unsigned short* __restrict__ qkvb,
                   const unsigned short* __restrict__ M2b,
                   const float* __restrict__ bias, float* __restrict__ C)
{
    __shared__ unsigned short As[128 * 32];
    __shared__ unsigned short Bs[128 * 32];
    const int t    = threadIdx.x;
    const int wave = t >> 6;
    const int lane = t & 63;
    const int b  = blockIdx.z;
    const int m0 = b * NN + blockIdx.y * 128;
    const int n0 = blockIdx.x * 128;
    const int wm = (wave >> 1) * 64;
    const int wn = (wave & 1) * 64;
    const int K = NDIM;

    f32x4_t acc[4][4] = {};

    const int srow = wave * 32 + (lane >> 2);
    const int scol = (lane & 3) * 8;
    const unsigned short* Ag = qkvb + (size_t)(m0 + srow) * QKVC + scol;
    const unsigned short* Bg = M2b + ((size_t)b * NDIM + n0 + srow) * NDIM + scol;
    unsigned short* sA = As + wave * 1024;
    unsigned short* sB = Bs + wave * 1024;

    const int fr = lane & 15;
    const int fq = (lane >> 4) * 8;

    for (int kt = 0; kt < K; kt += 32) {
        __syncthreads();
        GLOAD_LDS16(Ag + kt,             sA);
        GLOAD_LDS16(Ag + kt + (size_t)16 * QKVC, sA + 512);
        GLOAD_LDS16(Bg + kt,             sB);
        GLOAD_LDS16(Bg + kt + 16 * NDIM, sB + 512);
        __syncthreads();

        bf16x8_t af[4], bf[4];
        #pragma unroll
        for (int i = 0; i < 4; ++i) {
            af[i] = *(const bf16x8_t*)&As[(wm + i * 16 + fr) * 32 + fq];
            bf[i] = *(const bf16x8_t*)&Bs[(wn + i * 16 + fr) * 32 + fq];
        }
        #pragma unroll
        for (int i = 0; i < 4; ++i)
            #pragma unroll
            for (int j = 0; j < 4; ++j)
                acc[i][j] = __builtin_amdgcn_mfma_f32_16x16x32_bf16(
                    af[i], bf[j], acc[i][j], 0, 0, 0);
    }

    const int crow = (lane >> 4) * 4;
    const int ccol = lane & 15;
    #pragma unroll
    for (int j = 0; j < 4; ++j) {
        const int cn = n0 + wn + j * 16 + ccol;
        const float bb = bias[cn];
        #pragma unroll
        for (int i = 0; i < 4; ++i) {
            float* cp = C + (size_t)(m0 + wm + i * 16 + crow) * NDIM + cn;
            #pragma unroll
            for (int r = 0; r < 4; ++r)
                cp[(size_t)r * NDIM] = acc[i][j][r] + bb;
        }
    }
}

// ---------------------------------------------------------------------------
extern "C" void kernel_launch(void* const* d_in, const int* in_sizes, int n_in,
                              void* d_out, int out_size, void* d_ws, size_t ws_size,
                              hipStream_t stream)
{
    const float* x    = (const float*)d_in[0];
    const float* pos  = (const float*)d_in[1];
    const float* Wqkv = (const float*)d_in[2];
    const float* gk   = (const float*)d_in[3];
    const float* bk   = (const float*)d_in[4];
    const float* gv   = (const float*)d_in[5];
    const float* bv   = (const float*)d_in[6];
    const float* Wout = (const float*)d_in[7];
    const float* bout = (const float*)d_in[8];
    float* out = (float*)d_out;

    // ws: dots f32(1M) | dots_bf(0.5M) | M2b(4M) | qkvb(96M) | xb(32M) | W(2M)
    float* dots = (float*)d_ws;
    unsigned short* dots_bf = (unsigned short*)(dots + (size_t)NB * NH * 64 * 64);
    unsigned short* M2b     = dots_bf + (size_t)NB * NH * 64 * 64;
    unsigned short* qkvb    = M2b + (size_t)NB * NDIM * NDIM;
    unsigned short* xb      = qkvb + (size_t)NROWS * QKVC;
    unsigned short* Wqkvb   = xb + (size_t)NROWS * NDIM;
    unsigned short* Woutb   = Wqkvb + (size_t)QKVC * NDIM;

    hipMemsetAsync(dots, 0, (size_t)NB * NH * 64 * 64 * sizeof(float), stream);

    dim3 blk(256);
    // 0) fp32 -> bf16 converts
    cvt_bf16_kernel<<<dim3(NROWS * NDIM / 2048), blk, 0, stream>>>(x, xb, NROWS * NDIM);
    cvt_bf16_kernel<<<dim3(QKVC * NDIM / 2048), blk, 0, stream>>>(Wqkv, Wqkvb, QKVC * NDIM);
    cvt_bf16_kernel<<<dim3(NDIM * NDIM / 2048), blk, 0, stream>>>(Wout, Woutb, NDIM * NDIM);
    // 1) qkvb = post( x @ Wqkv^T )  -- LN(k,v) + RoPE(q,k) fused, bf16 out
    //    256x128 tile, 512 threads, 3-deep pipelined
    gemm_qkv_fused<<<dim3(QKVC / 128, NROWS / 256), dim3(512), 0, stream>>>(
        xb, Wqkvb, pos, gk, bk, gv, bv, qkvb);
    // 2) dots = k^T v per (b,h)
    dots_kernel<<<dim3(NN / 512, NH, NB), blk, 0, stream>>>(qkvb, dots);
    // 3) dots_bf = bf16(dots / N)
    cvt_dots_kernel<<<dim3(NB * NH * 64 * 64 / 1024), blk, 0, stream>>>(dots, dots_bf);
    // 4) M2b[b] = (dots_bf[b] @ blockdiag) x Wout^T  (bf16 MFMA)
    dotsw_mfma<<<dim3(NDIM / 128, NH, NB), blk, 0, stream>>>(Woutb, dots_bf, M2b);
    // 5) out = q @ M2b[b]^T + bout  (bf16 MFMA, fp32 out)
    gemm_out_mfma<<<dim3(NDIM / 128, NN / 128, NB), blk, 0, stream>>>(
        qkvb, M2b, bout, out);
}